// Round 5
// baseline (470.397 us; speedup 1.0000x reference)
//
#include <hip/hip_runtime.h>
#include <hip/hip_bf16.h>

// StochasticTernaryLinear: out = x @ ((sign(wp)-sign(wn))*0.5).T + bias
// B=524288, IN_F=128, OUT_F=128, all fp32 in/out.
// R4: swap MFMA operands (D = W·X^T) so the D fragment runs along out-cols
// -> dwordx4 stores (was 64 scalar dword stores); hoist all x (HBM) loads
// ahead of the K-loop for MLP; weights stay L2-hot per-kk loads.

typedef short short8 __attribute__((ext_vector_type(8)));
typedef float f32x4 __attribute__((ext_vector_type(4)));
typedef float f32x8 __attribute__((ext_vector_type(8)));

// fp32 -> bf16 bits, round-to-nearest-even (inputs are finite normals)
__device__ __forceinline__ short f2bf(float f) {
  unsigned u = __builtin_bit_cast(unsigned, f);
  unsigned r = u + 0x7fffu + ((u >> 16) & 1u);
  return (short)(r >> 16);
}

__global__ void ternarize_kernel(const float* __restrict__ wp,
                                 const float* __restrict__ wn,
                                 short* __restrict__ wt, int n) {
  int i = blockIdx.x * blockDim.x + threadIdx.x;
  if (i < n) {
    float p = wp[i];
    float q = wn[i];
    float v = 0.5f * ((p >= 0.f ? 1.f : -1.f) - (q >= 0.f ? 1.f : -1.f));
    wt[i] = f2bf(v);  // exactly -1, 0, +1 in bf16
  }
}

// Block: 256 threads = 4 waves. Block tile: 128 rows x 128 cols.
// Wave w owns rows [blk*128 + w*32, +32): 2 row-frags (m) x 8 col-frags (c).
// MFMA 16x16x32 bf16, operands: A = weight frag (M=out-cols), B = x frag
// (N=x-rows). D mapping: col(N)=lane&15 -> x-row r, row(M)=(lane>>4)*4+reg
// -> out-col g*4+reg. Per-thread D = 4 consecutive out-cols of one row.
__launch_bounds__(256, 2)
__global__ void stl_gemm_kernel(const float* __restrict__ x,
                                const short* __restrict__ wt,   // bf16 bits [128][128]
                                const float* __restrict__ bias,
                                float* __restrict__ out) {
  constexpr int IN_F = 128;
  constexpr int OUT_F = 128;
  const int wave = threadIdx.x >> 6;
  const int lane = threadIdx.x & 63;
  const int r = lane & 15;   // x-row within 16 (B-frag row / D col)
  const int g = lane >> 4;   // k-group (A/B frags), out-col group (D)
  const long row0 = (long)blockIdx.x * 128 + wave * 32;

  // Hoist the entire HBM x stream for this thread: 16 dwordx4 loads in flight.
  f32x8 xv[4][2];  // [kk][m] — all indices compile-time (full unroll)
#pragma unroll
  for (int kk = 0; kk < 4; ++kk)
#pragma unroll
    for (int m = 0; m < 2; ++m)
      xv[kk][m] = *(const f32x8*)(x + (row0 + m * 16 + r) * IN_F + kk * 32 + g * 8);

  f32x4 acc[2][8] = {};  // [m][c]

#pragma unroll
  for (int kk = 0; kk < 4; ++kk) {
    const int k0 = kk * 32 + g * 8;
    short8 bx[2];
#pragma unroll
    for (int m = 0; m < 2; ++m)
#pragma unroll
      for (int j = 0; j < 8; ++j) bx[m][j] = f2bf(xv[kk][m][j]);
#pragma unroll
    for (int c = 0; c < 8; ++c) {
      // A-frag: w[outcol = c*16 + r][k0 .. k0+7], L2-hot
      short8 aw = *(const short8*)(wt + (c * 16 + r) * IN_F + k0);
#pragma unroll
      for (int m = 0; m < 2; ++m)
        acc[m][c] =
            __builtin_amdgcn_mfma_f32_16x16x32_bf16(aw, bx[m], acc[m][c], 0, 0, 0);
    }
  }

  // Epilogue: thread (g, r) holds out[row0 + m*16 + r][c*16 + g*4 + 0..3]
#pragma unroll
  for (int c = 0; c < 8; ++c) {
    const f32x4 bv = *(const f32x4*)(bias + c * 16 + g * 4);
#pragma unroll
    for (int m = 0; m < 2; ++m) {
      f32x4 v = acc[m][c] + bv;
      *(f32x4*)(out + (row0 + m * 16 + r) * OUT_F + c * 16 + g * 4) = v;
    }
  }
}

extern "C" void kernel_launch(void* const* d_in, const int* in_sizes, int n_in,
                              void* d_out, int out_size, void* d_ws, size_t ws_size,
                              hipStream_t stream) {
  const float* x    = (const float*)d_in[0];
  const float* wp   = (const float*)d_in[1];
  const float* wn   = (const float*)d_in[2];
  const float* bias = (const float*)d_in[3];
  float* out = (float*)d_out;
  short* wt = (short*)d_ws;  // 128*128 bf16 = 32 KB scratch

  ternarize_kernel<<<64, 256, 0, stream>>>(wp, wn, wt, 128 * 128);

  // 524288 rows / 128 rows-per-block = 4096 blocks (exact, no tail)
  stl_gemm_kernel<<<4096, 256, 0, stream>>>(x, wt, bias, out);
}

// Round 6
// 455.613 us; speedup vs baseline: 1.0324x; 1.0324x over previous
//
#include <hip/hip_runtime.h>
#include <hip/hip_bf16.h>

// StochasticTernaryLinear: out = x @ ((sign(wp)-sign(wn))*0.5).T + bias
// B=524288, IN_F=128, OUT_F=128, fp32 in/out.
// R5: kill the latency chains seen in R4's counters (172us, 30% BW, all pipes
// idle, VGPR=68 => compiler sank the x loads):
//  - weights ternarized into FRAGMENT-ORDERED bf16 (wfrag[(kk*8+c)*64+lane]),
//    staged to LDS once per block via global_load_lds(16B), K-loop reads them
//    with contiguous conflict-free ds_read_b128 (no L2 latency in the chain).
//  - all 16 x-loads (f32x8) issued up front, pinned with sched_barrier(0);
//    __syncthreads' vmcnt(0) drain is the single memory-phase stall.
//    __launch_bounds__(256,2): 2 blocks/CU alternate load<->compute.

typedef short short8 __attribute__((ext_vector_type(8)));
typedef float f32x4 __attribute__((ext_vector_type(4)));
typedef float f32x8 __attribute__((ext_vector_type(8)));

// fp32 -> bf16 bits, round-to-nearest-even (inputs are finite normals)
__device__ __forceinline__ short f2bf(float f) {
  unsigned u = __builtin_bit_cast(unsigned, f);
  unsigned r = u + 0x7fffu + ((u >> 16) & 1u);
  return (short)(r >> 16);
}

// Emit ternary weights in MFMA A-fragment order:
// wfrag[chunk*64 + lane], chunk = kk*8 + c, holds
// w[outcol = c*16 + (lane&15)][k = kk*32 + (lane>>4)*8 + j], j=0..7.
__global__ void ternarize_frag_kernel(const float* __restrict__ wp,
                                      const float* __restrict__ wn,
                                      short8* __restrict__ wfrag) {
  const int tid = blockIdx.x * blockDim.x + threadIdx.x;  // 0..2047
  const int lane = tid & 63;
  const int chunk = tid >> 6;  // kk*8 + c
  const int kk = chunk >> 3, c = chunk & 7;
  const int r = lane & 15, g = lane >> 4;
  const int outcol = c * 16 + r;
  const int k0 = kk * 32 + g * 8;
  const float* p = wp + outcol * 128 + k0;
  const float* q = wn + outcol * 128 + k0;
  short8 v;
#pragma unroll
  for (int j = 0; j < 8; ++j) {
    float s = 0.5f * ((p[j] >= 0.f ? 1.f : -1.f) - (q[j] >= 0.f ? 1.f : -1.f));
    v[j] = f2bf(s);  // exactly -1, 0, +1 in bf16
  }
  wfrag[tid] = v;
}

// Block: 256 threads = 4 waves, tile 128 rows x 128 cols, wave owns 32 rows.
// MFMA 16x16x32 bf16, A = weight frag (M = out-cols), B = x frag (N = rows).
// D: col(N)=lane&15 -> x-row r, row(M)=(lane>>4)*4+reg -> out-col g*4+reg.
__launch_bounds__(256, 2)
__global__ void stl_gemm_kernel(const float* __restrict__ x,
                                const short8* __restrict__ wfrag,
                                const float* __restrict__ bias,
                                float* __restrict__ out) {
  constexpr int IN_F = 128;
  constexpr int OUT_F = 128;
  __shared__ short8 wlds[2048];  // 32 KB, fragment-ordered, linear
  const int tid = threadIdx.x;
  const int wave = tid >> 6;
  const int lane = tid & 63;
  const int r = lane & 15;
  const int g = lane >> 4;
  const long row0 = (long)blockIdx.x * 128 + wave * 32;

  // Stage weights global->LDS, async, linear dest (lane order == layout).
#pragma unroll
  for (int i = 0; i < 8; ++i) {
    const int chunk = i * 256 + tid;
    __builtin_amdgcn_global_load_lds(
        (const __attribute__((address_space(1))) void*)(wfrag + chunk),
        (__attribute__((address_space(3))) void*)(wlds + chunk),
        16, 0, 0);
  }

  // Issue the entire x stream for this thread (16 dwordx4-pairs in flight).
  f32x8 xv[4][2];  // [kk][m] — static indices only
#pragma unroll
  for (int kk = 0; kk < 4; ++kk)
#pragma unroll
    for (int m = 0; m < 2; ++m)
      xv[kk][m] =
          *(const f32x8*)(x + (row0 + m * 16 + r) * IN_F + kk * 32 + g * 8);
  __builtin_amdgcn_sched_barrier(0);  // pin: loads issue before anything below
  __syncthreads();  // vmcnt(0)+lgkmcnt(0): staging + x complete for all waves

  f32x4 acc[2][8] = {};  // [m][c]
#pragma unroll
  for (int kk = 0; kk < 4; ++kk) {
    short8 bx[2];
#pragma unroll
    for (int m = 0; m < 2; ++m)
#pragma unroll
      for (int j = 0; j < 8; ++j) bx[m][j] = f2bf(xv[kk][m][j]);
#pragma unroll
    for (int c = 0; c < 8; ++c) {
      const short8 aw = wlds[(kk * 8 + c) * 64 + lane];  // ds_read_b128
#pragma unroll
      for (int m = 0; m < 2; ++m)
        acc[m][c] =
            __builtin_amdgcn_mfma_f32_16x16x32_bf16(aw, bx[m], acc[m][c], 0, 0, 0);
    }
  }

  // Epilogue: thread (g,r) holds out[row0 + m*16 + r][c*16 + g*4 + 0..3]
#pragma unroll
  for (int c = 0; c < 8; ++c) {
    const f32x4 bv = *(const f32x4*)(bias + c * 16 + g * 4);
#pragma unroll
    for (int m = 0; m < 2; ++m) {
      f32x4 v = acc[m][c] + bv;
      *(f32x4*)(out + (row0 + m * 16 + r) * OUT_F + c * 16 + g * 4) = v;
    }
  }
}

extern "C" void kernel_launch(void* const* d_in, const int* in_sizes, int n_in,
                              void* d_out, int out_size, void* d_ws, size_t ws_size,
                              hipStream_t stream) {
  const float* x    = (const float*)d_in[0];
  const float* wp   = (const float*)d_in[1];
  const float* wn   = (const float*)d_in[2];
  const float* bias = (const float*)d_in[3];
  float* out = (float*)d_out;
  short8* wfrag = (short8*)d_ws;  // 2048 frags * 16 B = 32 KB scratch

  ternarize_frag_kernel<<<8, 256, 0, stream>>>(wp, wn, wfrag);

  // 524288 rows / 128 rows-per-block = 4096 blocks (exact, no tail)
  stl_gemm_kernel<<<4096, 256, 0, stream>>>(x, wfrag, bias, out);
}